// Round 1
// baseline (231.444 us; speedup 1.0000x reference)
//
#include <hip/hip_runtime.h>

// NURBS cubic surface eval: S=8,F=4 surfaces, Ncu=Ncv=32 control points,
// degree 3 both directions, uniform clamped knots -> knot[i]=clamp(i-3,0,29)/29.
// Per point: basis+deriv in u,v; 4x4 CP gather; pt, du, dv; normal=normalize(cross).
//
// Key facts exploited:
//  - All A2.3 recursion denominators are exact integer interval counts /29,
//    count in {1,2,3} -> replace fp32 divides with selected reciprocals.
//  - CP block per (s,f) is 32*32*3 floats = 12 KB -> stage in LDS as SoA
//    planes so the inner j-loop reads 4 consecutive dwords (ds_read2_b32).

#define NCP 32
#define KMAX 29              // n_unique - 1 = Ncp - deg

__device__ __forceinline__ float rcp29(int d) {
    // 29.0f / d for d in {1,2,3}
    return (d == 1) ? 29.0f : ((d == 2) ? 14.5f : (29.0f / 3.0f));
}

// Cubic basis values B0[0..3] and first derivatives B1[0..3] at parameter u,
// local span offset a = floor(u*29) in [0,28]. Transcription of NURBS Book
// A2.3 (p=3, n=1) with integer-exact denominators.
__device__ __forceinline__ void basis3(float u, int a, float B0[4], float B1[4]) {
    const float s = 1.0f / 29.0f;
    // knots at span+off, off in [-2,3]: clamp(a+off,0,29)/29. a+0,a+1 never clamp.
    float km2 = (float)max(a - 2, 0) * s;
    float km1 = (float)max(a - 1, 0) * s;
    float k00 = (float)a * s;
    float kp1 = (float)(a + 1) * s;
    float kp2 = (float)min(a + 2, KMAX) * s;
    float kp3 = (float)min(a + 3, KMAX) * s;
    float l1 = u - k00;   // left[1]
    float l2 = u - km1;   // left[2]
    float l3 = u - km2;   // left[3]
    float r1 = kp1 - u;   // right[1]
    float r2 = kp2 - u;   // right[2]
    float r3 = kp3 - u;   // right[3]
    // denominator reciprocals: d[j][r] = k(r+1)-k(r+1-j) as integer counts
    float q20 = rcp29(min(a + 1, 2));
    float q21 = rcp29(min(KMAX - a, 2));
    float q30 = rcp29(min(a + 1, 3));
    float q31 = rcp29(min(min(a + 2, 30 - a), 3));
    float q32 = rcp29(min(KMAX - a, 3));
    // j=1: temp = ndu[0][0]/d[1][0] = 1/(1/29) = 29
    float n01 = r1 * 29.0f;          // ndu[0][1]
    float n11 = l1 * 29.0f;          // ndu[1][1]
    // j=2
    float t = n01 * q20;
    float n02 = r1 * t;              // ndu[0][2]
    float sv = l2 * t;
    t = n11 * q21;
    float n12 = fmaf(r2, t, sv);     // ndu[1][2]
    float n22 = l1 * t;              // ndu[2][2]
    // j=3
    float t0 = n02 * q30;
    B0[0] = r1 * t0;
    sv = l3 * t0;
    float t1 = n12 * q31;
    B0[1] = fmaf(r2, t1, sv);
    sv = l2 * t1;
    float t2 = n22 * q32;
    B0[2] = fmaf(r3, t2, sv);
    B0[3] = l1 * t2;
    // first derivatives: ders1[r] = 3*(ndu[r-1][2]/d3[r-1] - ndu[r][2]/d3[r])
    B1[0] = -3.0f * t0;
    B1[1] = 3.0f * (t0 - t1);
    B1[2] = 3.0f * (t1 - t2);
    B1[3] = 3.0f * t2;
}

__global__ __launch_bounds__(256) void nurbs_eval_kernel(
    const float2* __restrict__ ev,   // [SF*P] (u,v)
    const float*  __restrict__ cp,   // [SF*32*32*3]
    float* __restrict__ out_pt,      // [SF*P*3]
    float* __restrict__ out_nrm,     // [SF*P*3]
    int P)
{
    __shared__ float sx[NCP * NCP];
    __shared__ float sy[NCP * NCP];
    __shared__ float sz[NCP * NCP];

    const int sf = blockIdx.y;
    // stage this surface's control points into SoA LDS planes
    const float* g = cp + (size_t)sf * (NCP * NCP * 3);
    for (int i = threadIdx.x; i < NCP * NCP; i += blockDim.x) {
        float c0 = g[3 * i + 0];
        float c1 = g[3 * i + 1];
        float c2 = g[3 * i + 2];
        sx[i] = c0; sy[i] = c1; sz[i] = c2;
    }
    __syncthreads();

    const int p = blockIdx.x * blockDim.x + threadIdx.x;
    if (p >= P) return;
    const int t = sf * P + p;

    float2 uv = ev[t];
    float u = uv.x, v = uv.y;
    int au = (int)floorf(u * 29.0f);
    int av = (int)floorf(v * 29.0f);
    au = min(max(au, 0), 28);
    av = min(max(av, 0), 28);

    float B0u[4], B1u[4], B0v[4], B1v[4];
    basis3(u, au, B0u, B1u);
    basis3(v, av, B0v, B1v);

    // separable contraction: j first (v direction), then i (u direction)
    float px = 0.f, py = 0.f, pz = 0.f;
    float ux = 0.f, uy = 0.f, uz = 0.f;
    float vx = 0.f, vy = 0.f, vz = 0.f;
    const int base = au * NCP + av;
#pragma unroll
    for (int i = 0; i < 4; ++i) {
        const int rb = base + i * NCP;
        float rpx = 0.f, rpy = 0.f, rpz = 0.f;
        float rvx = 0.f, rvy = 0.f, rvz = 0.f;
#pragma unroll
        for (int j = 0; j < 4; ++j) {
            float cx = sx[rb + j];
            float cy = sy[rb + j];
            float cz = sz[rb + j];
            float b0 = B0v[j], b1 = B1v[j];
            rpx = fmaf(b0, cx, rpx); rpy = fmaf(b0, cy, rpy); rpz = fmaf(b0, cz, rpz);
            rvx = fmaf(b1, cx, rvx); rvy = fmaf(b1, cy, rvy); rvz = fmaf(b1, cz, rvz);
        }
        float bu0 = B0u[i], bu1 = B1u[i];
        px = fmaf(bu0, rpx, px); py = fmaf(bu0, rpy, py); pz = fmaf(bu0, rpz, pz);
        ux = fmaf(bu1, rpx, ux); uy = fmaf(bu1, rpy, uy); uz = fmaf(bu1, rpz, uz);
        vx = fmaf(bu0, rvx, vx); vy = fmaf(bu0, rvy, vy); vz = fmaf(bu0, rvz, vz);
    }

    // normal = normalize(cross(du, dv))
    float nx = uy * vz - uz * vy;
    float ny = uz * vx - ux * vz;
    float nz = ux * vy - uy * vx;
    float len = sqrtf(nx * nx + ny * ny + nz * nz);
    float inv = 1.0f / (len + 1e-12f);
    nx *= inv; ny *= inv; nz *= inv;

    const int o = t * 3;
    out_pt[o + 0] = px;
    out_pt[o + 1] = py;
    out_pt[o + 2] = pz;
    out_nrm[o + 0] = nx;
    out_nrm[o + 1] = ny;
    out_nrm[o + 2] = nz;
}

extern "C" void kernel_launch(void* const* d_in, const int* in_sizes, int n_in,
                              void* d_out, int out_size, void* d_ws, size_t ws_size,
                              hipStream_t stream) {
    (void)n_in; (void)d_ws; (void)ws_size;
    const int SF = in_sizes[1] / (NCP * NCP * 3);   // S*F = 32
    const int P  = in_sizes[0] / (SF * 2);          // 200000
    const int N  = SF * P;                          // 6.4M points
    (void)out_size;                                 // == 2*N*3

    const float2* ev = (const float2*)d_in[0];
    const float*  cp = (const float*)d_in[1];
    float* out_pt  = (float*)d_out;
    float* out_nrm = (float*)d_out + (size_t)N * 3;

    dim3 block(256);
    dim3 grid((P + 255) / 256, SF);
    nurbs_eval_kernel<<<grid, block, 0, stream>>>(ev, cp, out_pt, out_nrm, P);
}

// Round 2
// 209.645 us; speedup vs baseline: 1.1040x; 1.1040x over previous
//
#include <hip/hip_runtime.h>

// NURBS cubic surface eval: S*F=32 surfaces, 32x32 CPs, degree 3, uniform
// clamped knots -> knot[i]=clamp(i-3,0,29)/29. Per point: basis+deriv in u,v;
// 4x4 CP patch contraction; pt, du, dv; normal=normalize(cross(du,dv)).
//
// Round-2 structure (post-mortem of R1: 41% of cycles were LDS conflict
// replay on 24+ narrow random-bank ds_reads/point):
//  - LDS holds SLIDING WINDOWS: win[row][c] = 12 floats of CPs [row][c..c+3]
//    xyz-interleaved as 3 aligned float4 -> per point 12 ds_read_b128 from a
//    single base VGPR with immediate offsets (192 B/point, no waste).
//  - 1024-thread blocks: 48 KB LDS x 2 blocks/CU = 32 waves/CU, 4x fewer
//    staging passes than 256-thread blocks.
//  - All A2.3 denominators are integer knot-interval counts /29 -> selected
//    reciprocal constants, zero divides. Normalize via v_sqrt+v_rcp builtins.

#define NCP 32
#define KMAX 29   // n_unique - 1 = Ncp - deg

__device__ __forceinline__ float rcp29(int d) {
    // 29.0f / d for d in {1,2,3}
    return (d == 1) ? 29.0f : ((d == 2) ? 14.5f : (29.0f / 3.0f));
}

// Cubic basis values B0[0..3] and first derivs B1[0..3] at u, span offset
// a = floor(u*29) in [0,28]. NURBS Book A2.3 (p=3,n=1), integer-exact denoms.
__device__ __forceinline__ void basis3(float u, int a, float B0[4], float B1[4]) {
    const float s = 1.0f / 29.0f;
    float km2 = (float)max(a - 2, 0) * s;
    float km1 = (float)max(a - 1, 0) * s;
    float k00 = (float)a * s;
    float kp1 = (float)(a + 1) * s;
    float kp2 = (float)min(a + 2, KMAX) * s;
    float kp3 = (float)min(a + 3, KMAX) * s;
    float l1 = u - k00, l2 = u - km1, l3 = u - km2;
    float r1 = kp1 - u, r2 = kp2 - u, r3 = kp3 - u;
    float q20 = rcp29(min(a + 1, 2));
    float q21 = rcp29(min(KMAX - a, 2));
    float q30 = rcp29(min(a + 1, 3));
    float q31 = rcp29(min(min(a + 2, 30 - a), 3));
    float q32 = rcp29(min(KMAX - a, 3));
    float n01 = r1 * 29.0f;
    float n11 = l1 * 29.0f;
    float t = n01 * q20;
    float n02 = r1 * t;
    float sv = l2 * t;
    t = n11 * q21;
    float n12 = fmaf(r2, t, sv);
    float n22 = l1 * t;
    float t0 = n02 * q30;
    B0[0] = r1 * t0;
    sv = l3 * t0;
    float t1 = n12 * q31;
    B0[1] = fmaf(r2, t1, sv);
    sv = l2 * t1;
    float t2 = n22 * q32;
    B0[2] = fmaf(r3, t2, sv);
    B0[3] = l1 * t2;
    B1[0] = -3.0f * t0;
    B1[1] = 3.0f * (t0 - t1);
    B1[2] = 3.0f * (t1 - t2);
    B1[3] = 3.0f * t2;
}

__global__ __launch_bounds__(1024, 8) void nurbs_eval_kernel(
    const float2* __restrict__ ev,   // [SF*P] (u,v)
    const float*  __restrict__ cp,   // [SF*32*32*3]
    float* __restrict__ out_pt,      // [SF*P*3]
    float* __restrict__ out_nrm,     // [SF*P*3]
    int P)
{
    // win[(row*32+c)*3 + q]: q=0:[x0 y0 z0 x1] q=1:[y1 z1 x2 y2] q=2:[z2 x3 y3 z3]
    __shared__ float4 win[NCP * NCP * 3];   // 48 KB

    const int sf = blockIdx.y;
    const float* g = cp + (size_t)sf * (NCP * NCP * 3);
    // build 32 rows x 29 window columns (c in [0,28]; av never exceeds 28)
    for (int idx = threadIdx.x; idx < NCP * 29; idx += blockDim.x) {
        int row = idx / 29;               // magic-mul, staging only
        int c   = idx - row * 29;
        const float* r = g + (row * NCP + c) * 3;
        float x0 = r[0], y0 = r[1],  z0 = r[2];
        float x1 = r[3], y1 = r[4],  z1 = r[5];
        float x2 = r[6], y2 = r[7],  z2 = r[8];
        float x3 = r[9], y3 = r[10], z3 = r[11];
        int w = (row * NCP + c) * 3;
        win[w + 0] = make_float4(x0, y0, z0, x1);
        win[w + 1] = make_float4(y1, z1, x2, y2);
        win[w + 2] = make_float4(z2, x3, y3, z3);
    }
    __syncthreads();

    const int p = blockIdx.x * blockDim.x + threadIdx.x;
    if (p >= P) return;
    const int t = sf * P + p;

    float2 uv = ev[t];
    int au = min((int)(uv.x * 29.0f), 28);
    int av = min((int)(uv.y * 29.0f), 28);

    float B0u[4], B1u[4], B0v[4], B1v[4];
    basis3(uv.x, au, B0u, B1u);
    basis3(uv.y, av, B0v, B1v);
    const float bv0 = B0v[0], bv1 = B0v[1], bv2 = B0v[2], bv3 = B0v[3];
    const float dv0 = B1v[0], dv1 = B1v[1], dv2 = B1v[2], dv3 = B1v[3];

    float px = 0.f, py = 0.f, pz = 0.f;
    float ux = 0.f, uy = 0.f, uz = 0.f;
    float vx = 0.f, vy = 0.f, vz = 0.f;
    const int base = (au * NCP + av) * 3;
#pragma unroll
    for (int i = 0; i < 4; ++i) {
        const float4 q0 = win[base + i * (NCP * 3) + 0];
        const float4 q1 = win[base + i * (NCP * 3) + 1];
        const float4 q2 = win[base + i * (NCP * 3) + 2];
        const float cx0 = q0.x, cy0 = q0.y, cz0 = q0.z;
        const float cx1 = q0.w, cy1 = q1.x, cz1 = q1.y;
        const float cx2 = q1.z, cy2 = q1.w, cz2 = q2.x;
        const float cx3 = q2.y, cy3 = q2.z, cz3 = q2.w;
        // v-direction contraction (point weights and v-deriv weights)
        float rpx = fmaf(bv3, cx3, fmaf(bv2, cx2, fmaf(bv1, cx1, bv0 * cx0)));
        float rpy = fmaf(bv3, cy3, fmaf(bv2, cy2, fmaf(bv1, cy1, bv0 * cy0)));
        float rpz = fmaf(bv3, cz3, fmaf(bv2, cz2, fmaf(bv1, cz1, bv0 * cz0)));
        float rvx = fmaf(dv3, cx3, fmaf(dv2, cx2, fmaf(dv1, cx1, dv0 * cx0)));
        float rvy = fmaf(dv3, cy3, fmaf(dv2, cy2, fmaf(dv1, cy1, dv0 * cy0)));
        float rvz = fmaf(dv3, cz3, fmaf(dv2, cz2, fmaf(dv1, cz1, dv0 * cz0)));
        // u-direction accumulate
        const float bu = B0u[i], du = B1u[i];
        px = fmaf(bu, rpx, px); py = fmaf(bu, rpy, py); pz = fmaf(bu, rpz, pz);
        ux = fmaf(du, rpx, ux); uy = fmaf(du, rpy, uy); uz = fmaf(du, rpz, uz);
        vx = fmaf(bu, rvx, vx); vy = fmaf(bu, rvy, vy); vz = fmaf(bu, rvz, vz);
    }

    // normal = cross(du, dv) / (|cross| + 1e-12)
    float nx = uy * vz - uz * vy;
    float ny = uz * vx - ux * vz;
    float nz = ux * vy - uy * vx;
    float d   = fmaf(nx, nx, fmaf(ny, ny, nz * nz));
    float len = __builtin_amdgcn_sqrtf(d);           // v_sqrt_f32, ~1ulp
    float inv = __builtin_amdgcn_rcpf(len + 1e-12f); // v_rcp_f32, ~1ulp
    nx *= inv; ny *= inv; nz *= inv;

    const int o = t * 3;
    out_pt[o + 0] = px;
    out_pt[o + 1] = py;
    out_pt[o + 2] = pz;
    out_nrm[o + 0] = nx;
    out_nrm[o + 1] = ny;
    out_nrm[o + 2] = nz;
}

extern "C" void kernel_launch(void* const* d_in, const int* in_sizes, int n_in,
                              void* d_out, int out_size, void* d_ws, size_t ws_size,
                              hipStream_t stream) {
    (void)n_in; (void)d_ws; (void)ws_size; (void)out_size;
    const int SF = in_sizes[1] / (NCP * NCP * 3);   // S*F = 32
    const int P  = in_sizes[0] / (SF * 2);          // 200000
    const int N  = SF * P;                          // 6.4M points

    const float2* ev = (const float2*)d_in[0];
    const float*  cp = (const float*)d_in[1];
    float* out_pt  = (float*)d_out;
    float* out_nrm = (float*)d_out + (size_t)N * 3;

    dim3 block(1024);
    dim3 grid((P + 1023) / 1024, SF);
    nurbs_eval_kernel<<<grid, block, 0, stream>>>(ev, cp, out_pt, out_nrm, P);
}